// Round 2
// baseline (423.033 us; speedup 1.0000x reference)
//
#include <hip/hip_runtime.h>
#include <hip/hip_bf16.h>
#include <stdint.h>

#define NB 32
#define NS 2048
#define NH 1024

typedef __attribute__((ext_vector_type(8))) unsigned short ushort8v;
typedef __attribute__((ext_vector_type(8))) __bf16 bf16x8;
typedef __attribute__((ext_vector_type(4))) float floatx4;

__device__ __forceinline__ unsigned short f2bf(float f) {
    union { float f; unsigned int u; } x; x.f = f;
    unsigned int r = x.u + 0x7fffu + ((x.u >> 16) & 1u);
    return (unsigned short)(r >> 16);
}

// ---------------- Kernel A: proj_s[b][d] = sum_k q[b][k] * Ws[k][d] (f32) ----
__global__ void projs_kernel(const float* __restrict__ q,
                             const float* __restrict__ Ws,
                             float* __restrict__ projs)
{
    int b  = blockIdx.x;          // 32
    int d0 = threadIdx.x * 4;     // 256 threads -> 1024 cols
    const float* qb = q + (size_t)b * NH;
    float4 acc = {0.f, 0.f, 0.f, 0.f};
    for (int k = 0; k < NH; ++k) {
        float qv = qb[k];
        float4 wv = *(const float4*)(Ws + (size_t)k * NH + d0);
        acc.x += qv * wv.x; acc.y += qv * wv.y;
        acc.z += qv * wv.z; acc.w += qv * wv.w;
    }
    *(float4*)(projs + (size_t)b * NH + d0) = acc;
}

// ---------------- Kernel B: scores[b][s] = v . tanh(E@Wh + proj_s) ----------
// BM=128 rows, BN=128 cols/iter, BK=32. 512 threads = 8 waves, each wave owns
// 16 rows x 128 cols (8 MFMA 16x16x32 frags). bf16 conversion on the fly.
__global__ __launch_bounds__(512) void scores_kernel(
    const float* __restrict__ E, const float* __restrict__ Wh,
    const float* __restrict__ projs, const float* __restrict__ v,
    const int* __restrict__ lens, float* __restrict__ scores)
{
    __shared__ __align__(16) unsigned short Asub[128][40];  // [row][k] bf16, +8 pad
    __shared__ __align__(16) unsigned short Wt[128][40];    // [n][k]  bf16 (transposed)

    const int tid  = threadIdx.x;
    const int brow = blockIdx.x * 128;          // global row in (B*S)
    const int b    = brow / NS;
    const int sloc = brow % NS;
    const int len  = lens[b];
    if (sloc >= len) return;                    // fully masked block: scores never read

    const int wid = tid >> 6;                   // 0..7
    const int lane = tid & 63;
    const int l15 = lane & 15;
    const int l16 = lane >> 4;                  // 0..3

    // staging coords
    const int ar  = tid >> 2;                   // 0..127  (A row)
    const int ak  = (tid & 3) << 3;             // 0,8,16,24
    const int wn  = tid & 127;                  // 0..127  (W col)
    const int wkb = (tid >> 7) << 3;            // 0,8,16,24

    const float* Eb = E + (size_t)brow * NH;
    float scorep[4] = {0.f, 0.f, 0.f, 0.f};

    for (int nb = 0; nb < NH / 128; ++nb) {     // 8 column blocks
        const int n0 = nb * 128;
        floatx4 acc[8];
        #pragma unroll
        for (int c = 0; c < 8; ++c) acc[c] = (floatx4){0.f, 0.f, 0.f, 0.f};

        for (int k0 = 0; k0 < NH; k0 += 32) {   // 32 K-steps
            __syncthreads();
            // stage A tile (128x32 f32 -> bf16)
            {
                const float* asrc = Eb + (size_t)ar * NH + (k0 + ak);
                float4 a0 = *(const float4*)asrc;
                float4 a1 = *(const float4*)(asrc + 4);
                ushort8v av;
                av[0] = f2bf(a0.x); av[1] = f2bf(a0.y);
                av[2] = f2bf(a0.z); av[3] = f2bf(a0.w);
                av[4] = f2bf(a1.x); av[5] = f2bf(a1.y);
                av[6] = f2bf(a1.z); av[7] = f2bf(a1.w);
                *(ushort8v*)&Asub[ar][ak] = av;
            }
            // stage W tile transposed (32x128 f32 -> Wt[n][k] bf16)
            {
                const float* wsrc = Wh + (size_t)(k0 + wkb) * NH + (n0 + wn);
                ushort8v wv;
                #pragma unroll
                for (int j = 0; j < 8; ++j) wv[j] = f2bf(wsrc[(size_t)j * NH]);
                *(ushort8v*)&Wt[wn][wkb] = wv;
            }
            __syncthreads();

            bf16x8 af = __builtin_bit_cast(bf16x8,
                *(const ushort8v*)&Asub[wid * 16 + l15][l16 * 8]);
            #pragma unroll
            for (int c = 0; c < 8; ++c) {
                bf16x8 bfr = __builtin_bit_cast(bf16x8,
                    *(const ushort8v*)&Wt[c * 16 + l15][l16 * 8]);
                acc[c] = __builtin_amdgcn_mfma_f32_16x16x32_bf16(af, bfr, acc[c], 0, 0, 0);
            }
        }
        // epilogue fold: score += v[n] * tanh(acc + proj_s[b][n])
        #pragma unroll
        for (int c = 0; c < 8; ++c) {
            int col = n0 + c * 16 + l15;
            float ps = projs[(size_t)b * NH + col];
            float vv = v[col];
            #pragma unroll
            for (int i = 0; i < 4; ++i)
                scorep[i] += tanhf(acc[c][i] + ps) * vv;
        }
    }
    // reduce over the 16 lanes (l15) sharing each row; D row = l16*4 + i
    #pragma unroll
    for (int i = 0; i < 4; ++i) {
        float s = scorep[i];
        s += __shfl_xor(s, 1);
        s += __shfl_xor(s, 2);
        s += __shfl_xor(s, 4);
        s += __shfl_xor(s, 8);
        if (l15 == 0)
            scores[(size_t)brow + wid * 16 + l16 * 4 + i] = s;
    }
}

// ---------------- Kernel C1: masked softmax over S per batch ----------------
__global__ void softmax_kernel(const float* __restrict__ scores,
                               const int* __restrict__ lens,
                               float* __restrict__ wts)
{
    int b = blockIdx.x, tid = threadIdx.x;      // 32 blocks x 256 threads
    int len = lens[b];
    const float* sb = scores + (size_t)b * NS;
    float loc[8];
    float mx = -3e38f;
    #pragma unroll
    for (int i = 0; i < 8; ++i) {
        int s = tid + i * 256;
        float val = (s < len) ? sb[s] : -1e9f;
        loc[i] = val;
        mx = fmaxf(mx, val);
    }
    #pragma unroll
    for (int m = 32; m >= 1; m >>= 1) mx = fmaxf(mx, __shfl_xor(mx, m));
    __shared__ float red[4], red2[4];
    int w = tid >> 6;
    if ((tid & 63) == 0) red[w] = mx;
    __syncthreads();
    mx = fmaxf(fmaxf(red[0], red[1]), fmaxf(red[2], red[3]));
    float sum = 0.f;
    #pragma unroll
    for (int i = 0; i < 8; ++i) { loc[i] = expf(loc[i] - mx); sum += loc[i]; }
    #pragma unroll
    for (int m = 32; m >= 1; m >>= 1) sum += __shfl_xor(sum, m);
    if ((tid & 63) == 0) red2[w] = sum;
    __syncthreads();
    sum = red2[0] + red2[1] + red2[2] + red2[3];
    float inv = 1.f / sum;
    #pragma unroll
    for (int i = 0; i < 8; ++i)
        wts[(size_t)b * NS + tid + i * 256] = loc[i] * inv;
}

// ---------------- Kernel C2: out[b][h] = sum_s w[b][s] * E[b][s][h] ---------
__global__ void attnout_kernel(const float* __restrict__ E,
                               const float* __restrict__ wts,
                               float* __restrict__ out)
{
    int b  = blockIdx.x >> 4;                   // 32 batches x 16 s-chunks
    int s0 = (blockIdx.x & 15) * 128;
    int t  = threadIdx.x;                       // 256
    __shared__ float wsh[128];
    __shared__ int anyw;
    if (t == 0) anyw = 0;
    __syncthreads();
    if (t < 128) {
        float w = wts[(size_t)b * NS + s0 + t];
        wsh[t] = w;
        if (w != 0.f) anyw = 1;
    }
    __syncthreads();
    if (!anyw) return;                          // chunk has exactly-zero weights
    int h0 = t * 4;
    const float* Eb = E + ((size_t)b * NS + s0) * NH + h0;
    float4 acc = {0.f, 0.f, 0.f, 0.f};
    for (int s = 0; s < 128; ++s) {
        float w = wsh[s];
        float4 e = *(const float4*)(Eb + (size_t)s * NH);
        acc.x += w * e.x; acc.y += w * e.y;
        acc.z += w * e.z; acc.w += w * e.w;
    }
    float* o = out + (size_t)b * NH + h0;
    atomicAdd(o + 0, acc.x); atomicAdd(o + 1, acc.y);
    atomicAdd(o + 2, acc.z); atomicAdd(o + 3, acc.w);
}

// ---------------- launch ----------------------------------------------------
extern "C" void kernel_launch(void* const* d_in, const int* in_sizes, int n_in,
                              void* d_out, int out_size, void* d_ws, size_t ws_size,
                              hipStream_t stream)
{
    const float* q    = (const float*)d_in[0];
    const float* E    = (const float*)d_in[1];
    const int*   lens = (const int*)d_in[2];
    const float* Wh   = (const float*)d_in[3];
    const float* Ws   = (const float*)d_in[4];
    const float* v    = (const float*)d_in[5];
    float* out = (float*)d_out;

    float* ws     = (float*)d_ws;
    float* projs  = ws;                    // 32*1024
    float* scores = ws + 32 * 1024;        // 32*2048
    float* wts    = scores + 32 * 2048;    // 32*2048

    hipMemsetAsync(d_out, 0, (size_t)out_size * sizeof(float), stream);
    projs_kernel  <<<NB, 256, 0, stream>>>(q, Ws, projs);
    scores_kernel <<<(NB * NS) / 128, 512, 0, stream>>>(E, Wh, projs, v, lens, scores);
    softmax_kernel<<<NB, 256, 0, stream>>>(scores, lens, wts);
    attnout_kernel<<<NB * 16, 256, 0, stream>>>(E, wts, out);
}

// Round 4
// 294.159 us; speedup vs baseline: 1.4381x; 1.4381x over previous
//
#include <hip/hip_runtime.h>
#include <hip/hip_bf16.h>
#include <stdint.h>

#define NB 32
#define NS 2048
#define NH 1024

typedef __attribute__((ext_vector_type(8))) unsigned short ushort8v;
typedef __attribute__((ext_vector_type(8))) __bf16 bf16x8;
typedef __attribute__((ext_vector_type(4))) float floatx4;

__device__ __forceinline__ unsigned short f2bf(float f) {
    union { float f; unsigned int u; } x; x.f = f;
    unsigned int r = x.u + 0x7fffu + ((x.u >> 16) & 1u);
    return (unsigned short)(r >> 16);
}
__device__ __forceinline__ float tanh_fast(float x) {
    float e2 = __expf(2.0f * x);                 // v_exp_f32 path
    return 1.0f - 2.0f * __builtin_amdgcn_rcpf(e2 + 1.0f);
}

// ---------- Kernel W: pack Wh (f32 [k][n]) -> WhP bf16 blocks ----------------
// WhP[n>>4][k>>5][(n&15)*32 + (k&31)]  -- each (16n x 32k) MFMA B-block is a
// contiguous 1 KB so a wave's B-frag load is one coalesced dwordx4.
__global__ void convw_kernel(const float* __restrict__ Wh,
                             unsigned short* __restrict__ WhP)
{
    int kb = blockIdx.x;                  // 128 blocks * 8 k-rows
    int t  = threadIdx.x;                 // 256
    int n  = t * 4;
    int ni = n & 15, nh = n >> 4;
    for (int i = 0; i < 8; ++i) {
        int k = kb * 8 + i;
        float4 w = *(const float4*)(Wh + (size_t)k * NH + n);
        size_t base = (size_t)nh * 16384 + (size_t)(k >> 5) * 512 + (k & 31);
        WhP[base + (size_t)(ni + 0) * 32] = f2bf(w.x);
        WhP[base + (size_t)(ni + 1) * 32] = f2bf(w.y);
        WhP[base + (size_t)(ni + 2) * 32] = f2bf(w.z);
        WhP[base + (size_t)(ni + 3) * 32] = f2bf(w.w);
    }
}

// ---------- Kernel A: proj_s = q @ Ws (f32, tiny) ---------------------------
__global__ void projs_kernel(const float* __restrict__ q,
                             const float* __restrict__ Ws,
                             float* __restrict__ projs)
{
    int b  = blockIdx.x;
    int d0 = threadIdx.x * 4;
    const float* qb = q + (size_t)b * NH;
    float4 acc = {0.f, 0.f, 0.f, 0.f};
    for (int k = 0; k < NH; ++k) {
        float qv = qb[k];
        float4 wv = *(const float4*)(Ws + (size_t)k * NH + d0);
        acc.x += qv * wv.x; acc.y += qv * wv.y;
        acc.z += qv * wv.z; acc.w += qv * wv.w;
    }
    *(float4*)(projs + (size_t)b * NH + d0) = acc;
}

// ---------- Kernel B: scores = v . tanh(E@Wh + proj_s), E read ONCE ---------
// BM=64 rows/block, full N=1024 accumulated (8 waves x 128 cols), K in two
// 512-chunks staged to swizzled LDS [kk][64][32]. B streamed from WhP (L2).
__global__ __launch_bounds__(512, 1) void scores_kernel(
    const float* __restrict__ E, const unsigned short* __restrict__ WhP,
    const float* __restrict__ projs, const float* __restrict__ v,
    const int* __restrict__ lens, float* __restrict__ scores)
{
    __shared__ __align__(16) unsigned short A16[16 * 64 * 32]; // 64 KB
    __shared__ float sc[8][64];

    const int tid  = threadIdx.x;
    const int brow = blockIdx.x * 64;
    const int b    = brow >> 11;
    const int sloc = brow & (NS - 1);
    const int len  = lens[b];
    if (sloc >= len) return;               // block-uniform

    const int wid = tid >> 6;
    const int lane = tid & 63;
    const int l15 = lane & 15;
    const int l16 = lane >> 4;

    floatx4 acc[4][8];
    #pragma unroll
    for (int m = 0; m < 4; ++m)
        #pragma unroll
        for (int c = 0; c < 8; ++c) acc[m][c] = (floatx4){0.f, 0.f, 0.f, 0.f};

    // swizzled LDS read base (shorts): row l15, slot (l16*8)^((l15&3)<<3)
    const unsigned short* abase = A16 + l15 * 32 + ((l16 * 8) ^ ((l15 & 3) << 3));
    // B base: wave owns n_hi in [wid*8, wid*8+8).
    // MFMA B-frag: lane holds col (n&15)=l15, k = l16*8..+7 -> offset l15*32+l16*8
    const unsigned short* bbase = WhP + (size_t)wid * 8 * 16384 + l15 * 32 + l16 * 8;

    const float* Eb = E + (size_t)brow * NH;

    ushort8v breg[2][8];

    for (int kc = 0; kc < 2; ++kc) {
        __syncthreads();
        // stage 64 rows x 512 k of E, f32 -> bf16, swizzled; coalesced reads
        #pragma unroll
        for (int i = 0; i < 8; ++i) {
            int e  = (i * 512 + tid) * 8;      // chunk element
            int r  = e >> 9;
            int k0 = e & 511;
            const float* src = Eb + (size_t)r * NH + kc * 512 + k0;
            float4 f0 = *(const float4*)src;
            float4 f1 = *(const float4*)(src + 4);
            ushort8v uv;
            uv[0] = f2bf(f0.x); uv[1] = f2bf(f0.y);
            uv[2] = f2bf(f0.z); uv[3] = f2bf(f0.w);
            uv[4] = f2bf(f1.x); uv[5] = f2bf(f1.y);
            uv[6] = f2bf(f1.z); uv[7] = f2bf(f1.w);
            int kk = k0 >> 5, ks = k0 & 31;    // ks in {0,8,16,24}
            *(ushort8v*)(A16 + kk * 2048 + r * 32 + (ks ^ ((r & 3) << 3))) = uv;
        }
        __syncthreads();

        #pragma unroll
        for (int c = 0; c < 8; ++c)
            breg[0][c] = *(const ushort8v*)(bbase + (size_t)c * 16384 + (kc * 16) * 512);

        #pragma unroll
        for (int kk = 0; kk < 16; ++kk) {
            if (kk < 15) {
                #pragma unroll
                for (int c = 0; c < 8; ++c)
                    breg[(kk + 1) & 1][c] = *(const ushort8v*)
                        (bbase + (size_t)c * 16384 + (kc * 16 + kk + 1) * 512);
            }
            bf16x8 a[4];
            #pragma unroll
            for (int m = 0; m < 4; ++m)
                a[m] = __builtin_bit_cast(bf16x8,
                    *(const ushort8v*)(abase + kk * 2048 + m * 512));
            #pragma unroll
            for (int m = 0; m < 4; ++m)
                #pragma unroll
                for (int c = 0; c < 8; ++c)
                    acc[m][c] = __builtin_amdgcn_mfma_f32_16x16x32_bf16(
                        a[m], __builtin_bit_cast(bf16x8, breg[kk & 1][c]),
                        acc[m][c], 0, 0, 0);
        }
    }

    // epilogue: score_row += v[col] * tanh(acc + proj_s[col])
    float psv[8], vv[8];
    #pragma unroll
    for (int c = 0; c < 8; ++c) {
        int col = wid * 128 + c * 16 + l15;
        psv[c] = projs[(size_t)b * NH + col];
        vv[c]  = v[col];
    }
    float sp[4][4];
    #pragma unroll
    for (int m = 0; m < 4; ++m)
        #pragma unroll
        for (int r = 0; r < 4; ++r) sp[m][r] = 0.f;
    #pragma unroll
    for (int m = 0; m < 4; ++m)
        #pragma unroll
        for (int c = 0; c < 8; ++c)
            #pragma unroll
            for (int r = 0; r < 4; ++r)
                sp[m][r] += tanh_fast(acc[m][c][r] + psv[c]) * vv[c];

    #pragma unroll
    for (int m = 0; m < 4; ++m)
        #pragma unroll
        for (int r = 0; r < 4; ++r) {
            float s = sp[m][r];
            s += __shfl_xor(s, 1);
            s += __shfl_xor(s, 2);
            s += __shfl_xor(s, 4);
            s += __shfl_xor(s, 8);
            if (l15 == 0) sc[wid][m * 16 + l16 * 4 + r] = s;
        }
    __syncthreads();
    if (tid < 64) {
        float s = 0.f;
        #pragma unroll
        for (int w = 0; w < 8; ++w) s += sc[w][tid];
        scores[(size_t)brow + tid] = s;
    }
}

// ---------- Kernel C1: masked softmax ---------------------------------------
__global__ void softmax_kernel(const float* __restrict__ scores,
                               const int* __restrict__ lens,
                               float* __restrict__ wts)
{
    int b = blockIdx.x, tid = threadIdx.x;
    int len = lens[b];
    const float* sb = scores + (size_t)b * NS;
    float loc[8];
    float mx = -3e38f;
    #pragma unroll
    for (int i = 0; i < 8; ++i) {
        int s = tid + i * 256;
        float val = (s < len) ? sb[s] : -1e9f;
        loc[i] = val;
        mx = fmaxf(mx, val);
    }
    #pragma unroll
    for (int m = 32; m >= 1; m >>= 1) mx = fmaxf(mx, __shfl_xor(mx, m));
    __shared__ float red[4], red2[4];
    int w = tid >> 6;
    if ((tid & 63) == 0) red[w] = mx;
    __syncthreads();
    mx = fmaxf(fmaxf(red[0], red[1]), fmaxf(red[2], red[3]));
    float sum = 0.f;
    #pragma unroll
    for (int i = 0; i < 8; ++i) { loc[i] = expf(loc[i] - mx); sum += loc[i]; }
    #pragma unroll
    for (int m = 32; m >= 1; m >>= 1) sum += __shfl_xor(sum, m);
    if ((tid & 63) == 0) red2[w] = sum;
    __syncthreads();
    sum = red2[0] + red2[1] + red2[2] + red2[3];
    float inv = 1.f / sum;
    #pragma unroll
    for (int i = 0; i < 8; ++i)
        wts[(size_t)b * NS + tid + i * 256] = loc[i] * inv;
}

// ---------- Kernel C2: out = wts @ E ----------------------------------------
__global__ void attnout_kernel(const float* __restrict__ E,
                               const float* __restrict__ wts,
                               float* __restrict__ out)
{
    int b  = blockIdx.x >> 4;
    int s0 = (blockIdx.x & 15) * 128;
    int t  = threadIdx.x;
    __shared__ float wsh[128];
    __shared__ int anyw;
    if (t == 0) anyw = 0;
    __syncthreads();
    if (t < 128) {
        float w = wts[(size_t)b * NS + s0 + t];
        wsh[t] = w;
        if (w != 0.f) anyw = 1;
    }
    __syncthreads();
    if (!anyw) return;
    int h0 = t * 4;
    const float* Eb = E + ((size_t)b * NS + s0) * NH + h0;
    float4 acc = {0.f, 0.f, 0.f, 0.f};
    for (int s = 0; s < 128; ++s) {
        float w = wsh[s];
        float4 e = *(const float4*)(Eb + (size_t)s * NH);
        acc.x += w * e.x; acc.y += w * e.y;
        acc.z += w * e.z; acc.w += w * e.w;
    }
    float* o = out + (size_t)b * NH + h0;
    atomicAdd(o + 0, acc.x); atomicAdd(o + 1, acc.y);
    atomicAdd(o + 2, acc.z); atomicAdd(o + 3, acc.w);
}

// ---------- launch ----------------------------------------------------------
extern "C" void kernel_launch(void* const* d_in, const int* in_sizes, int n_in,
                              void* d_out, int out_size, void* d_ws, size_t ws_size,
                              hipStream_t stream)
{
    const float* q    = (const float*)d_in[0];
    const float* E    = (const float*)d_in[1];
    const int*   lens = (const int*)d_in[2];
    const float* Wh   = (const float*)d_in[3];
    const float* Ws   = (const float*)d_in[4];
    const float* v    = (const float*)d_in[5];
    float* out = (float*)d_out;

    float* ws     = (float*)d_ws;
    float* projs  = ws;                          // 32K floats
    float* scores = ws + 32 * 1024;              // 64K floats
    float* wts    = scores + 32 * 2048;          // 64K floats
    unsigned short* WhP = (unsigned short*)(wts + 32 * 2048);  // 2 MB

    hipMemsetAsync(d_out, 0, (size_t)out_size * sizeof(float), stream);
    convw_kernel  <<<128, 256, 0, stream>>>(Wh, WhP);
    projs_kernel  <<<NB, 256, 0, stream>>>(q, Ws, projs);
    scores_kernel <<<(NB * NS) / 64, 512, 0, stream>>>(E, WhP, projs, v, lens, scores);
    softmax_kernel<<<NB, 256, 0, stream>>>(scores, lens, wts);
    attnout_kernel<<<NB * 16, 256, 0, stream>>>(E, wts, out);
}